// Round 1
// baseline (2129.128 us; speedup 1.0000x reference)
//
#include <hip/hip_runtime.h>
#include <math.h>

// Problem constants
#define B_   16
#define D_   128
#define N_   8192
#define KS_  5
#define W_   128
#define EPS_ 1e-5f
#define SCALE_ 0.08838834764831845f   // 128^-0.5

// Workspace layout (float offsets). Total = 59,867,392 floats = 239.5 MB.
#define OFF_QA    0UL          // q (B,N,D), later aliased as attention output a
#define OFF_K     16777216UL   // k rotated (B,N,D)
#define OFF_V     33554432UL   // v (B,N,D)
#define OFF_ROPE  50331648UL   // N x 128: [cos(64) | sin(64)] per position
#define OFF_MEANP 51380224UL   // 512 x 128 partial column sums
#define OFF_SP    51445760UL   // 512 x 16384 partial S = sum a a^T
#define OFF_MEAN  59834368UL   // 128
#define OFF_S     59834496UL   // 16384
#define OFF_W2    59850880UL   // 16384 folded 1x1-conv weights
#define OFF_B2    59867264UL   // 128 folded bias

// ---------------------------------------------------------------------------
// Rope table: phase computed in double, reduced mod 2pi, fp32 trig.
// ---------------------------------------------------------------------------
__global__ __launch_bounds__(64) void rope_kernel(float* __restrict__ rope) {
  const int j = threadIdx.x;       // 0..63 (frequency)
  const int n = blockIdx.x;        // 0..N-1 (position)
  double inv = pow(10000.0, -(double)j * (1.0 / 64.0));
  double ph = (double)n * inv;
  const double TWO_PI = 6.283185307179586476925286766559;
  ph -= TWO_PI * floor(ph / TWO_PI);
  float phf = (float)ph;
  rope[(size_t)n * 128 + j]      = cosf(phf);
  rope[(size_t)n * 128 + 64 + j] = sinf(phf);
}

// ---------------------------------------------------------------------------
// Fused causal conv1d for q,k,v + rotary (q,k) + q-scale.
// Block: 256 threads; one (batch, 128-position tile). LDS x tile reused 3x.
// Thread tile: 8 channels (as 4 rotary pairs (d, d+64)) x 8 positions.
// ---------------------------------------------------------------------------
__global__ __launch_bounds__(256, 2) void conv_qkv_kernel(
    const float* __restrict__ x,
    const float* __restrict__ qw, const float* __restrict__ qb,
    const float* __restrict__ kw, const float* __restrict__ kb,
    const float* __restrict__ vw, const float* __restrict__ vb,
    const float* __restrict__ rope,
    float* __restrict__ qo, float* __restrict__ ko, float* __restrict__ vo)
{
  __shared__ float xs[128][132];          // 128 in-ch x (128+4) positions
  const int b  = blockIdx.y;
  const int n0 = blockIdx.x * 128;
  const int tid = threadIdx.x;

  for (int idx = tid; idx < 128 * 132; idx += 256) {
    int i  = idx / 132;
    int jc = idx - i * 132;
    int n  = n0 - 4 + jc;
    xs[i][jc] = (n >= 0) ? x[((size_t)b * 128 + i) * N_ + n] : 0.f;
  }
  __syncthreads();

  const int co = tid >> 4;   // 0..15: channel pair group (co*4..+3, 64+co*4..+3)
  const int po = tid & 15;   // 0..15: position group (po*8..+7)

  for (int c = 0; c < 3; ++c) {
    const float* w    = (c == 0) ? qw : (c == 1) ? kw : vw;
    const float* bias = (c == 0) ? qb : (c == 1) ? kb : vb;
    float* outp       = (c == 0) ? qo : (c == 1) ? ko : vo;

    float acc[8][8];
    #pragma unroll
    for (int cc = 0; cc < 8; ++cc) {
      int o = (cc < 4) ? (co * 4 + cc) : (64 + co * 4 + cc - 4);
      float bv = bias[o];
      #pragma unroll
      for (int pp = 0; pp < 8; ++pp) acc[cc][pp] = bv;
    }

    for (int i = 0; i < 128; ++i) {
      float xv[12];
      const float4* xr = (const float4*)(&xs[i][po * 8]);
      float4 x0 = xr[0], x1 = xr[1], x2 = xr[2];
      xv[0] = x0.x; xv[1] = x0.y; xv[2]  = x0.z; xv[3]  = x0.w;
      xv[4] = x1.x; xv[5] = x1.y; xv[6]  = x1.z; xv[7]  = x1.w;
      xv[8] = x2.x; xv[9] = x2.y; xv[10] = x2.z; xv[11] = x2.w;
      #pragma unroll
      for (int cc = 0; cc < 8; ++cc) {
        int o = (cc < 4) ? (co * 4 + cc) : (64 + co * 4 + cc - 4);
        const float* wp = w + (size_t)o * 640 + i * 5;
        float w0 = wp[0], w1 = wp[1], w2 = wp[2], w3 = wp[3], w4 = wp[4];
        #pragma unroll
        for (int pp = 0; pp < 8; ++pp) {
          float s = acc[cc][pp];
          s = fmaf(w0, xv[pp],     s);
          s = fmaf(w1, xv[pp + 1], s);
          s = fmaf(w2, xv[pp + 2], s);
          s = fmaf(w3, xv[pp + 3], s);
          s = fmaf(w4, xv[pp + 4], s);
          acc[cc][pp] = s;
        }
      }
    }

    if (c == 2) {            // v: store plain
      #pragma unroll
      for (int pp = 0; pp < 8; ++pp) {
        int n = n0 + po * 8 + pp;
        float* dst = outp + ((size_t)b * N_ + n) * 128;
        *(float4*)(dst + co * 4)      = make_float4(acc[0][pp], acc[1][pp], acc[2][pp], acc[3][pp]);
        *(float4*)(dst + 64 + co * 4) = make_float4(acc[4][pp], acc[5][pp], acc[6][pp], acc[7][pp]);
      }
    } else {                 // q/k: rotary (+ scale for q)
      float sc = (c == 0) ? SCALE_ : 1.f;
      #pragma unroll
      for (int pp = 0; pp < 8; ++pp) {
        int n = n0 + po * 8 + pp;
        const float* rr = rope + (size_t)n * 128 + co * 4;
        float4 cv = *(const float4*)(rr);
        float4 sv = *(const float4*)(rr + 64);
        float cA[4] = {cv.x, cv.y, cv.z, cv.w};
        float sA[4] = {sv.x, sv.y, sv.z, sv.w};
        float lo[4], hi[4];
        #pragma unroll
        for (int jj = 0; jj < 4; ++jj) {
          lo[jj] = (acc[jj][pp]     * cA[jj] - acc[jj + 4][pp] * sA[jj]) * sc;
          hi[jj] = (acc[jj + 4][pp] * cA[jj] + acc[jj][pp]     * sA[jj]) * sc;
        }
        float* dst = outp + ((size_t)b * N_ + n) * 128;
        *(float4*)(dst + co * 4)      = make_float4(lo[0], lo[1], lo[2], lo[3]);
        *(float4*)(dst + 64 + co * 4) = make_float4(hi[0], hi[1], hi[2], hi[3]);
      }
    }
  }
}

// ---------------------------------------------------------------------------
// Local causal attention. Block: 64 q rows, 256 threads.
// Scores to LDS, wave-parallel softmax, PV with coalesced v reads.
// aout may alias q (each block reads only its own q rows before writing).
// ---------------------------------------------------------------------------
__global__ __launch_bounds__(256, 2) void attn_kernel(
    const float* __restrict__ q, const float* __restrict__ k,
    const float* __restrict__ v, float* __restrict__ aout)
{
  __shared__ float sim[64][260];   // stride 260: f4-aligned, conflict-friendly
  __shared__ float rinv[64];
  const int b   = blockIdx.y;
  const int n0  = blockIdx.x * 64;
  const int w0  = n0 >> 7;
  const int kstart = w0 * 128 - 128;
  const int tid = threadIdx.x;
  const int tq = tid >> 4, tk = tid & 15;

  const float* qb_ = q + ((size_t)b * N_) * 128;
  const float* kb_ = k + ((size_t)b * N_) * 128;
  const float* vb_ = v + ((size_t)b * N_) * 128;

  // Phase 1: sim = q . k^T  (q pre-scaled, both pre-rotated by conv kernel)
  for (int g = 0; g < 4; ++g) {
    float acc[4][4];
    #pragma unroll
    for (int a = 0; a < 4; ++a)
      #pragma unroll
      for (int u = 0; u < 4; ++u) acc[a][u] = 0.f;

    #pragma unroll 2
    for (int d4 = 0; d4 < 32; ++d4) {
      float4 qv[4], kv[4];
      #pragma unroll
      for (int qq = 0; qq < 4; ++qq)
        qv[qq] = *(const float4*)(qb_ + (size_t)(n0 + tq + 16 * qq) * 128 + d4 * 4);
      #pragma unroll
      for (int u = 0; u < 4; ++u) {
        int nk = kstart + g * 64 + tk + 16 * u;   // may be <0: safe garbage, masked below
        kv[u] = *(const float4*)(kb_ + (size_t)nk * 128 + d4 * 4);
      }
      #pragma unroll
      for (int qq = 0; qq < 4; ++qq)
        #pragma unroll
        for (int u = 0; u < 4; ++u) {
          acc[qq][u] = fmaf(qv[qq].x, kv[u].x, acc[qq][u]);
          acc[qq][u] = fmaf(qv[qq].y, kv[u].y, acc[qq][u]);
          acc[qq][u] = fmaf(qv[qq].z, kv[u].z, acc[qq][u]);
          acc[qq][u] = fmaf(qv[qq].w, kv[u].w, acc[qq][u]);
        }
    }
    #pragma unroll
    for (int qq = 0; qq < 4; ++qq) {
      int nq = n0 + tq + 16 * qq;
      #pragma unroll
      for (int u = 0; u < 4; ++u) {
        int jj = g * 64 + tk + 16 * u;
        int nk = kstart + jj;
        sim[tq + 16 * qq][jj] = (nk >= 0 && nk <= nq) ? acc[qq][u] : -3.4028235e38f;
      }
    }
  }
  __syncthreads();

  // Phase 2: softmax (4 lanes per row, stride-4 scan to dodge bank conflicts)
  {
    const int row = tid >> 2, part = tid & 3;
    float m = -3.4028235e38f;
    for (int i = 0; i < 64; ++i) m = fmaxf(m, sim[row][part + 4 * i]);
    m = fmaxf(m, __shfl_xor(m, 1));
    m = fmaxf(m, __shfl_xor(m, 2));
    float s = 0.f;
    for (int i = 0; i < 64; ++i) {
      float p = __expf(sim[row][part + 4 * i] - m);
      sim[row][part + 4 * i] = p;
      s += p;
    }
    s += __shfl_xor(s, 1);
    s += __shfl_xor(s, 2);
    if (part == 0) rinv[row] = 1.f / s;   // diag always valid -> s >= ~1
  }
  __syncthreads();

  // Phase 3: out = P . v  (thread dims: 4tk..4tk+3 and 64+4tk..+3)
  float o0[4][4], o1[4][4];
  #pragma unroll
  for (int qq = 0; qq < 4; ++qq)
    #pragma unroll
    for (int dd = 0; dd < 4; ++dd) { o0[qq][dd] = 0.f; o1[qq][dd] = 0.f; }

  const int j0 = (kstart < 0) ? 128 : 0;   // window 0: prev block fully masked
  #pragma unroll 2
  for (int j = j0; j < 256; ++j) {
    size_t vrow = (size_t)(kstart + j) * 128;
    float4 va = *(const float4*)(vb_ + vrow + 4 * tk);
    float4 vb2 = *(const float4*)(vb_ + vrow + 64 + 4 * tk);
    #pragma unroll
    for (int qq = 0; qq < 4; ++qq) {
      float p = sim[tq + 16 * qq][j];
      o0[qq][0] = fmaf(p, va.x,  o0[qq][0]);
      o0[qq][1] = fmaf(p, va.y,  o0[qq][1]);
      o0[qq][2] = fmaf(p, va.z,  o0[qq][2]);
      o0[qq][3] = fmaf(p, va.w,  o0[qq][3]);
      o1[qq][0] = fmaf(p, vb2.x, o1[qq][0]);
      o1[qq][1] = fmaf(p, vb2.y, o1[qq][1]);
      o1[qq][2] = fmaf(p, vb2.z, o1[qq][2]);
      o1[qq][3] = fmaf(p, vb2.w, o1[qq][3]);
    }
  }

  #pragma unroll
  for (int qq = 0; qq < 4; ++qq) {
    int nq = n0 + tq + 16 * qq;
    float inv = rinv[tq + 16 * qq];
    float* dst = aout + ((size_t)b * N_ + nq) * 128;
    *(float4*)(dst + 4 * tk)      = make_float4(o0[qq][0] * inv, o0[qq][1] * inv,
                                                o0[qq][2] * inv, o0[qq][3] * inv);
    *(float4*)(dst + 64 + 4 * tk) = make_float4(o1[qq][0] * inv, o1[qq][1] * inv,
                                                o1[qq][2] * inv, o1[qq][3] * inv);
  }
}

// ---------------------------------------------------------------------------
// BN stats part 1: per-block partial colsum(a) and S = sum a a^T.
// 512 blocks x 256 rows each.
// ---------------------------------------------------------------------------
__global__ __launch_bounds__(256, 2) void stats_kernel(
    const float* __restrict__ a, float* __restrict__ Sp, float* __restrict__ meanp)
{
  __shared__ float as8[8][132];
  const int bk = blockIdx.x;
  const size_t m0 = (size_t)bk * 256;
  const int tid = threadIdx.x;
  const int ti = tid >> 4, tj = tid & 15;

  float acc[8][8];
  #pragma unroll
  for (int ii = 0; ii < 8; ++ii)
    #pragma unroll
    for (int jj = 0; jj < 8; ++jj) acc[ii][jj] = 0.f;
  float csum = 0.f;

  for (int bt = 0; bt < 32; ++bt) {
    {
      int rr = tid >> 5, c4 = tid & 31;
      float4 vx = *(const float4*)(a + (m0 + bt * 8 + rr) * 128 + c4 * 4);
      *(float4*)(&as8[rr][c4 * 4]) = vx;
    }
    __syncthreads();
    #pragma unroll
    for (int rr = 0; rr < 8; ++rr) {
      const float4* pi = (const float4*)(&as8[rr][ti * 8]);
      const float4* pj = (const float4*)(&as8[rr][tj * 8]);
      float4 i0 = pi[0], i1 = pi[1], j0v = pj[0], j1v = pj[1];
      float ai[8] = {i0.x, i0.y, i0.z, i0.w, i1.x, i1.y, i1.z, i1.w};
      float aj[8] = {j0v.x, j0v.y, j0v.z, j0v.w, j1v.x, j1v.y, j1v.z, j1v.w};
      #pragma unroll
      for (int ii = 0; ii < 8; ++ii)
        #pragma unroll
        for (int jj = 0; jj < 8; ++jj)
          acc[ii][jj] = fmaf(ai[ii], aj[jj], acc[ii][jj]);
    }
    if (tid < 128) {
      #pragma unroll
      for (int rr = 0; rr < 8; ++rr) csum += as8[rr][tid];
    }
    __syncthreads();
  }

  float* dstS = Sp + (size_t)bk * 16384;
  #pragma unroll
  for (int ii = 0; ii < 8; ++ii) {
    *(float4*)(dstS + (ti * 8 + ii) * 128 + tj * 8)     = make_float4(acc[ii][0], acc[ii][1], acc[ii][2], acc[ii][3]);
    *(float4*)(dstS + (ti * 8 + ii) * 128 + tj * 8 + 4) = make_float4(acc[ii][4], acc[ii][5], acc[ii][6], acc[ii][7]);
  }
  if (tid < 128) meanp[bk * 128 + tid] = csum;
}

// BN stats part 2: reduce partials.
__global__ __launch_bounds__(256) void reduce_kernel(
    const float* __restrict__ Sp, const float* __restrict__ meanp,
    float* __restrict__ S, float* __restrict__ mean)
{
  const int e = blockIdx.x * 256 + threadIdx.x;
  float s = 0.f;
  for (int bk = 0; bk < 512; ++bk) s += Sp[(size_t)bk * 16384 + e];
  S[e] = s;
  if (blockIdx.x == 0 && threadIdx.x < 128) {
    float ms = 0.f;
    for (int bk = 0; bk < 512; ++bk) ms += meanp[bk * 128 + threadIdx.x];
    mean[threadIdx.x] = ms * (1.f / (float)(B_ * N_));
  }
}

// BN fold: var_y[o] = w_o^T Cov w_o; fold gamma*rsqrt into 1x1 weights.
__global__ __launch_bounds__(256) void fold_kernel(
    const float* __restrict__ S, const float* __restrict__ mean,
    const float* __restrict__ ow, const float* __restrict__ ob,
    const float* __restrict__ gamma, const float* __restrict__ beta,
    float* __restrict__ w2, float* __restrict__ b2)
{
  __shared__ float scl[128];
  const int o = threadIdx.x >> 1, half = threadIdx.x & 1;
  const float* wo = ow + o * 128;
  float quad = 0.f, dm = 0.f;
  for (int i = half * 64; i < half * 64 + 64; ++i) {
    float wi = wo[i];
    float t = 0.f;
    for (int jj = 0; jj < 128; ++jj) t = fmaf(S[i * 128 + jj], wo[jj], t);
    quad = fmaf(wi, t, quad);
    dm   = fmaf(wi, mean[i], dm);
  }
  quad += __shfl_xor(quad, 1);
  dm   += __shfl_xor(dm, 1);
  if (half == 0) {
    float var = quad * (1.f / (float)(B_ * N_)) - dm * dm;
    var = fmaxf(var, 0.f);
    float sc = gamma[o] * rsqrtf(var + EPS_);
    scl[o] = sc;
    b2[o] = beta[o] - sc * dm;   // (o_b cancels against mean_y)
  }
  __syncthreads();
  for (int e = (int)threadIdx.x; e < 16384; e += 256)
    w2[e] = scl[e >> 7] * ow[e];
}

// Final 1x1 conv with folded BN, writes (B,D,N).
__global__ __launch_bounds__(256, 2) void out_kernel(
    const float* __restrict__ a, const float* __restrict__ w2,
    const float* __restrict__ b2, float* __restrict__ out)
{
  __shared__ float at[128][132];   // transposed a tile: [in_ch][pos]
  const int b  = blockIdx.y;
  const int n0 = blockIdx.x * 128;
  const int tid = threadIdx.x;
  {
    int row = tid >> 1, half = tid & 1;
    const float* src = a + ((size_t)b * N_ + n0 + row) * 128 + half * 64;
    #pragma unroll
    for (int qq = 0; qq < 16; ++qq) {
      float4 vx = *(const float4*)(src + qq * 4);
      int i = half * 64 + qq * 4;
      at[i][row] = vx.x; at[i + 1][row] = vx.y; at[i + 2][row] = vx.z; at[i + 3][row] = vx.w;
    }
  }
  __syncthreads();

  const int co = tid >> 4, po = tid & 15;
  float acc[8][8];
  #pragma unroll
  for (int cc = 0; cc < 8; ++cc) {
    float bv = b2[co * 8 + cc];
    #pragma unroll
    for (int pp = 0; pp < 8; ++pp) acc[cc][pp] = bv;
  }
  for (int i = 0; i < 128; ++i) {
    const float4* xr = (const float4*)(&at[i][po * 8]);
    float4 x0 = xr[0], x1 = xr[1];
    float xv[8] = {x0.x, x0.y, x0.z, x0.w, x1.x, x1.y, x1.z, x1.w};
    #pragma unroll
    for (int cc = 0; cc < 8; ++cc) {
      float wv = w2[(co * 8 + cc) * 128 + i];
      #pragma unroll
      for (int pp = 0; pp < 8; ++pp) acc[cc][pp] = fmaf(wv, xv[pp], acc[cc][pp]);
    }
  }
  #pragma unroll
  for (int cc = 0; cc < 8; ++cc) {
    int o = co * 8 + cc;
    float* dst = out + ((size_t)b * 128 + o) * N_ + n0 + po * 8;
    *(float4*)(dst)     = make_float4(acc[cc][0], acc[cc][1], acc[cc][2], acc[cc][3]);
    *(float4*)(dst + 4) = make_float4(acc[cc][4], acc[cc][5], acc[cc][6], acc[cc][7]);
  }
}

// ---------------------------------------------------------------------------
extern "C" void kernel_launch(void* const* d_in, const int* in_sizes, int n_in,
                              void* d_out, int out_size, void* d_ws, size_t ws_size,
                              hipStream_t stream)
{
  const float* x     = (const float*)d_in[0];
  const float* qw    = (const float*)d_in[1];
  const float* qb    = (const float*)d_in[2];
  const float* kw    = (const float*)d_in[3];
  const float* kb    = (const float*)d_in[4];
  const float* vw    = (const float*)d_in[5];
  const float* vb    = (const float*)d_in[6];
  const float* ow    = (const float*)d_in[7];
  const float* ob    = (const float*)d_in[8];
  const float* gamma = (const float*)d_in[9];
  const float* beta  = (const float*)d_in[10];
  float* out = (float*)d_out;
  float* ws  = (float*)d_ws;

  float* q     = ws + OFF_QA;
  float* k     = ws + OFF_K;
  float* v     = ws + OFF_V;
  float* rope  = ws + OFF_ROPE;
  float* meanp = ws + OFF_MEANP;
  float* Sp    = ws + OFF_SP;
  float* mean  = ws + OFF_MEAN;
  float* S     = ws + OFF_S;
  float* w2    = ws + OFF_W2;
  float* b2    = ws + OFF_B2;

  rope_kernel<<<N_, 64, 0, stream>>>(rope);

  dim3 gconv(N_ / 128, B_);
  conv_qkv_kernel<<<gconv, 256, 0, stream>>>(x, qw, qb, kw, kb, vw, vb, rope, q, k, v);

  dim3 gattn(N_ / 64, B_);
  attn_kernel<<<gattn, 256, 0, stream>>>(q, k, v, q /* aout aliases q */);

  stats_kernel<<<512, 256, 0, stream>>>(q, Sp, meanp);
  reduce_kernel<<<64, 256, 0, stream>>>(Sp, meanp, S, mean);
  fold_kernel<<<1, 256, 0, stream>>>(S, mean, ow, ob, gamma, beta, w2, b2);

  dim3 gout(N_ / 128, B_);
  out_kernel<<<gout, 256, 0, stream>>>(q, w2, b2, out);
}

// Round 4
// 771.694 us; speedup vs baseline: 2.7590x; 2.7590x over previous
//
#include <hip/hip_runtime.h>
#include <math.h>

#define B_   16
#define D_   128
#define N_   8192
#define EPS_ 1e-5f
#define SCALE_ 0.08838834764831845f   // 128^-0.5
#define NEG_ -3.4028235e38f

typedef _Float16 half8 __attribute__((ext_vector_type(8)));
typedef _Float16 half4 __attribute__((ext_vector_type(4)));
typedef float f32x16 __attribute__((ext_vector_type(16)));
#define MFMA32(a,b,c) __builtin_amdgcn_mfma_f32_32x32x16_f16(a,b,c,0,0,0)

// Workspace layout (float offsets).
#define OFF_QA    0UL          // q (B,N,D) f16; aliased as attention output a
#define OFF_K     8388608UL    // k (B,N,D) f16 (pre-rotary)
#define OFF_VT    16777216UL   // v transposed (B,D,N) f16
#define OFF_ROPE  25165824UL   // N x 64 pairs (cos,sin) f32
#define OFF_WB    26214400UL   // prepacked conv weights f16 [c][t][o][i]
#define OFF_INVF  26337280UL   // 64 f32
#define OFF_SP    26337344UL   // 512 x 16384 partial S
#define OFF_MEANP 34725952UL   // 512 x 128
#define OFF_MEAN  34791488UL
#define OFF_S     34791616UL
#define OFF_W2    34808000UL
#define OFF_B2    34824384UL

// XOR-swizzled LDS index (stride 128 halfs, 16-byte blocks XOR'd by row&7)
__device__ __forceinline__ int swz(int row, int col) {
  return row * 128 + ((((col >> 3) ^ (row & 7))) << 3) + (col & 7);
}

// ---------------------------------------------------------------------------
__global__ __launch_bounds__(64) void invf_kernel(float* __restrict__ invf) {
  int j = threadIdx.x;
  invf[j] = (float)pow(10000.0, -(double)j / 64.0);
}

__global__ __launch_bounds__(256) void rope2_kernel(const float* __restrict__ invf,
                                                    float* __restrict__ rope2) {
  int idx = blockIdx.x * 256 + threadIdx.x;   // n*64 + j
  int n = idx >> 6, j = idx & 63;
  float ph = (float)n * invf[j];              // fp32 like jax
  rope2[(size_t)n * 128 + 2 * j]     = cosf(ph);
  rope2[(size_t)n * 128 + 2 * j + 1] = sinf(ph);
}

__global__ __launch_bounds__(128) void prepack_kernel(
    const float* __restrict__ qw, const float* __restrict__ kw,
    const float* __restrict__ vw, _Float16* __restrict__ WB) {
  int o = blockIdx.x, t = blockIdx.y, c = blockIdx.z, i = threadIdx.x;
  const float* w = (c == 0) ? qw : (c == 1) ? kw : vw;
  float v = w[(o * 128 + i) * 5 + t] * (c == 0 ? SCALE_ : 1.f);
  WB[(((size_t)(c * 5 + t) * 128 + o) * 128) + i] = (_Float16)v;
}

// ---------------------------------------------------------------------------
// Fused q/k/v causal conv as 5 shifted K=128 f16 GEMMs (32x32x16 MFMA).
// Block: 256 thr (4 waves), 128 positions x 128 outputs. Wave: 32 pos x 128 o.
// q,k stored (B,N,D) f16; v stored transposed (B,D,N) f16.
// ---------------------------------------------------------------------------
__global__ __launch_bounds__(256, 2) void conv_kernel(
    const float* __restrict__ x, const _Float16* __restrict__ WB,
    const float* __restrict__ qb, const float* __restrict__ kb_,
    const float* __restrict__ vb,
    _Float16* __restrict__ qo, _Float16* __restrict__ ko,
    _Float16* __restrict__ vT)
{
  __shared__ _Float16 xs[132 * 128];   // [pos padded j][chan] swizzled
  __shared__ _Float16 wb[128 * 128];   // [o][i] swizzled
  const int b = blockIdx.y, n0 = blockIdx.x * 128;
  const int tid = threadIdx.x;
  const int lane = tid & 63, wq = tid >> 6;
  const int l31 = lane & 31, h = lane >> 5;

  { // stage x tile: transpose + f16 + swizzle
    int i = tid >> 1, g = tid & 1;
    const float* xrow = x + ((size_t)b * 128 + i) * (size_t)N_;
    int j0 = g * 66;
    for (int m = 0; m < 66; ++m) {
      int j = j0 + m, n = n0 - 4 + j;
      float v = (n >= 0) ? xrow[n] : 0.f;
      xs[swz(j, i)] = (_Float16)v;
    }
  }

  for (int c = 0; c < 3; ++c) {
    f32x16 acc[4];
    #pragma unroll
    for (int nt = 0; nt < 4; ++nt)
      #pragma unroll
      for (int u = 0; u < 16; ++u) acc[nt][u] = 0.f;

    for (int t = 0; t < 5; ++t) {
      __syncthreads();
      { // stage weights for (c,t): 32 KB
        const _Float16* src = WB + ((size_t)(c * 5 + t) << 14);
        #pragma unroll
        for (int m = 0; m < 8; ++m) {
          int idx = m * 256 + tid;
          int o = idx >> 4, ip = idx & 15;
          half8 v = *(const half8*)(src + o * 128 + ip * 8);
          *(half8*)(wb + o * 128 + ((ip ^ (o & 7)) << 3)) = v;
        }
      }
      __syncthreads();
      const int arow = wq * 32 + l31 + t;
      const int r7a = arow & 7;
      #pragma unroll
      for (int kb2 = 0; kb2 < 8; ++kb2) {
        half8 av = *(const half8*)(xs + arow * 128 + ((((kb2 * 2 + h) ^ r7a)) << 3));
        #pragma unroll
        for (int nt = 0; nt < 4; ++nt) {
          int o = nt * 32 + l31;
          half8 bv = *(const half8*)(wb + o * 128 + ((((kb2 * 2 + h) ^ (o & 7))) << 3));
          acc[nt] = MFMA32(av, bv, acc[nt]);
        }
      }
    }

    if (c < 2) {
      const float* bias = (c == 0) ? qb : kb_;
      float bsc = (c == 0) ? SCALE_ : 1.f;
      _Float16* outp = (c == 0) ? qo : ko;
      #pragma unroll
      for (int nt = 0; nt < 4; ++nt) {
        int o = nt * 32 + l31;
        float bv = bias[o] * bsc;
        #pragma unroll
        for (int reg = 0; reg < 16; ++reg) {
          int pos = wq * 32 + (reg & 3) + 8 * (reg >> 2) + 4 * h;
          outp[((size_t)b * N_ + n0 + pos) * 128 + o] = (_Float16)(acc[nt][reg] + bv);
        }
      }
    } else {
      // v: transpose via xs reuse -> (B,D,N)
      __syncthreads();
      #pragma unroll
      for (int nt = 0; nt < 4; ++nt) {
        int o = nt * 32 + l31;
        float bv = vb[o];
        #pragma unroll
        for (int reg = 0; reg < 16; ++reg) {
          int pos = wq * 32 + (reg & 3) + 8 * (reg >> 2) + 4 * h;
          xs[swz(o, pos)] = (_Float16)(acc[nt][reg] + bv);
        }
      }
      __syncthreads();
      int o2 = tid >> 1, g2 = tid & 1;
      _Float16* dst = vT + ((size_t)b * 128 + o2) * (size_t)N_ + n0 + g2 * 64;
      #pragma unroll
      for (int m = 0; m < 8; ++m) {
        int pos = g2 * 64 + m * 8;
        half8 v = *(const half8*)(xs + o2 * 128 + ((((pos >> 3) ^ (o2 & 7))) << 3));
        *(half8*)(dst + m * 8) = v;
      }
    }
  }
}

// ---------------------------------------------------------------------------
// Local causal attention, f16 MFMA, flash-style over 2 key chunks.
// Block: 512 thr (8 waves: wr 0..3 x wc 0..1), 128 q rows (one window).
// Rotary applied during q/k LDS staging.
// ---------------------------------------------------------------------------
__device__ __forceinline__ void stage_rot(const _Float16* __restrict__ src_base,
                                          _Float16* __restrict__ dst,
                                          const float* __restrict__ rope2,
                                          int nbase, int tid)
{
  int row = tid >> 2, p = tid & 3;
  const _Float16* src = src_base + (size_t)row * 128;
  const float* rp = rope2 + ((size_t)(nbase + row)) * 128 + p * 32;
  half8 lo0 = *(const half8*)(src + p * 16);
  half8 lo1 = *(const half8*)(src + p * 16 + 8);
  half8 hi0 = *(const half8*)(src + 64 + p * 16);
  half8 hi1 = *(const half8*)(src + 64 + p * 16 + 8);
  half8 olo0, olo1, ohi0, ohi1;
  #pragma unroll
  for (int u = 0; u < 8; ++u) {
    float c0 = rp[2 * u], s0 = rp[2 * u + 1];
    float c1 = rp[16 + 2 * u], s1 = rp[16 + 2 * u + 1];
    float xl0 = (float)lo0[u], xh0 = (float)hi0[u];
    float xl1 = (float)lo1[u], xh1 = (float)hi1[u];
    olo0[u] = (_Float16)(xl0 * c0 - xh0 * s0);
    ohi0[u] = (_Float16)(xh0 * c0 + xl0 * s0);
    olo1[u] = (_Float16)(xl1 * c1 - xh1 * s1);
    ohi1[u] = (_Float16)(xh1 * c1 + xl1 * s1);
  }
  int r7 = row & 7;
  *(half8*)(dst + row * 128 + (((p * 2)     ^ r7) << 3)) = olo0;
  *(half8*)(dst + row * 128 + (((p * 2 + 1) ^ r7) << 3)) = olo1;
  *(half8*)(dst + row * 128 + (((8 + p * 2) ^ r7) << 3)) = ohi0;
  *(half8*)(dst + row * 128 + (((9 + p * 2) ^ r7) << 3)) = ohi1;
}

__device__ __forceinline__ void stage_vT(const _Float16* __restrict__ vsrc,
                                         _Float16* __restrict__ dst, int tid)
{
  int d = tid >> 2, p = tid & 3;
  const _Float16* src = vsrc + (size_t)d * (size_t)N_;
  int r7 = d & 7;
  #pragma unroll
  for (int m = 0; m < 4; ++m) {
    int kp = m * 32 + p * 8;
    half8 v = *(const half8*)(src + kp);
    *(half8*)(dst + d * 128 + ((((kp >> 3) ^ r7)) << 3)) = v;
  }
}

__global__ __launch_bounds__(512, 2) void attn_kernel(
    const _Float16* __restrict__ q, const _Float16* __restrict__ k,
    const _Float16* __restrict__ vT, const float* __restrict__ rope2,
    _Float16* __restrict__ aout)
{
  __shared__ _Float16 q_s[128 * 128];
  __shared__ _Float16 k_s[128 * 128];
  __shared__ _Float16 vT_s[128 * 128];
  __shared__ _Float16 P_s[128 * 128];
  __shared__ float red_m[2][128];
  __shared__ float red_s[2][128];

  const int b = blockIdx.y, w = blockIdx.x;
  const int tid = threadIdx.x, lane = tid & 63, wid = tid >> 6;
  const int wr = wid >> 1, wc = wid & 1;
  const int l31 = lane & 31, h = lane >> 5;

  stage_rot(q + ((size_t)b * N_ + w * 128) * 128, q_s, rope2, w * 128, tid);

  float mrun[16], lrun[16];
  f32x16 O[2];
  #pragma unroll
  for (int r = 0; r < 16; ++r) { mrun[r] = NEG_; lrun[r] = 0.f; O[0][r] = 0.f; O[1][r] = 0.f; }

  const int qrow = wr * 32 + l31;
  const int r7q = qrow & 7;
  int rowof[16];
  #pragma unroll
  for (int r = 0; r < 16; ++r) rowof[r] = wr * 32 + (r & 3) + 8 * (r >> 2) + 4 * h;

  for (int ch = (w == 0 ? 1 : 0); ch < 2; ++ch) {
    int kv0 = w * 128 - 128 + ch * 128;
    __syncthreads();   // protect k_s/vT_s vs prev PV; covers q_s staging on 1st iter
    stage_rot(k + ((size_t)b * N_ + kv0) * 128, k_s, rope2, kv0, tid);
    stage_vT(vT + (size_t)b * 128 * (size_t)N_ + kv0, vT_s, tid);
    __syncthreads();

    // QK^T
    f32x16 sim[2];
    #pragma unroll
    for (int r = 0; r < 16; ++r) { sim[0][r] = 0.f; sim[1][r] = 0.f; }
    #pragma unroll
    for (int kb2 = 0; kb2 < 8; ++kb2) {
      half8 av = *(const half8*)(q_s + qrow * 128 + ((((kb2 * 2 + h) ^ r7q)) << 3));
      #pragma unroll
      for (int nt = 0; nt < 2; ++nt) {
        int krow = wc * 64 + nt * 32 + l31;
        half8 bv = *(const half8*)(k_s + krow * 128 + ((((kb2 * 2 + h) ^ (krow & 7))) << 3));
        sim[nt] = MFMA32(av, bv, sim[nt]);
      }
    }
    if (ch == 1) {  // causal mask within current window
      #pragma unroll
      for (int nt = 0; nt < 2; ++nt) {
        int col = wc * 64 + nt * 32 + l31;
        #pragma unroll
        for (int r = 0; r < 16; ++r)
          if (col > rowof[r]) sim[nt][r] = NEG_;
      }
    }

    // row max (this wave's 64 cols)
    float pm[16];
    #pragma unroll
    for (int r = 0; r < 16; ++r) pm[r] = fmaxf(sim[0][r], sim[1][r]);
    #pragma unroll
    for (int m = 1; m <= 16; m <<= 1)
      #pragma unroll
      for (int r = 0; r < 16; ++r) pm[r] = fmaxf(pm[r], __shfl_xor(pm[r], m));
    if (l31 == 0) {
      #pragma unroll
      for (int r = 0; r < 16; ++r) red_m[wc][rowof[r]] = pm[r];
    }
    __syncthreads();

    float scale[16], ps[16];
    #pragma unroll
    for (int r = 0; r < 16; ++r) {
      float mc = fmaxf(red_m[0][rowof[r]], red_m[1][rowof[r]]);
      float mn = fmaxf(mrun[r], mc);
      scale[r] = __expf(mrun[r] - mn);
      mrun[r] = mn;
      ps[r] = 0.f;
    }
    #pragma unroll
    for (int nt = 0; nt < 2; ++nt) {
      int col = wc * 64 + nt * 32 + l31;
      #pragma unroll
      for (int r = 0; r < 16; ++r) {
        float p = __expf(sim[nt][r] - mrun[r]);
        ps[r] += p;
        P_s[swz(rowof[r], col)] = (_Float16)p;
      }
    }
    #pragma unroll
    for (int m = 1; m <= 16; m <<= 1)
      #pragma unroll
      for (int r = 0; r < 16; ++r) ps[r] += __shfl_xor(ps[r], m);
    if (l31 == 0) {
      #pragma unroll
      for (int r = 0; r < 16; ++r) red_s[wc][rowof[r]] = ps[r];
    }
    __syncthreads();

    #pragma unroll
    for (int r = 0; r < 16; ++r) {
      float ss = red_s[0][rowof[r]] + red_s[1][rowof[r]];
      lrun[r] = lrun[r] * scale[r] + ss;
      O[0][r] *= scale[r];
      O[1][r] *= scale[r];
    }

    // PV
    #pragma unroll
    for (int kb2 = 0; kb2 < 8; ++kb2) {
      half8 pa = *(const half8*)(P_s + qrow * 128 + ((((kb2 * 2 + h) ^ r7q)) << 3));
      #pragma unroll
      for (int nt = 0; nt < 2; ++nt) {
        int drow = wc * 64 + nt * 32 + l31;
        half8 bv = *(const half8*)(vT_s + drow * 128 + ((((kb2 * 2 + h) ^ (drow & 7))) << 3));
        O[nt] = MFMA32(pa, bv, O[nt]);
      }
    }
  }

  // epilogue: normalize, store f16 (B,N,D)
  #pragma unroll
  for (int nt = 0; nt < 2; ++nt) {
    int col = wc * 64 + nt * 32 + l31;
    #pragma unroll
    for (int r = 0; r < 16; ++r) {
      float inv = 1.f / lrun[r];
      aout[((size_t)b * N_ + w * 128 + rowof[r]) * 128 + col] = (_Float16)(O[nt][r] * inv);
    }
  }
}

// ---------------------------------------------------------------------------
// BN stats part 1 (f16 input): partial colsum(a) and S = sum a a^T.
// ---------------------------------------------------------------------------
__global__ __launch_bounds__(256, 2) void stats_kernel(
    const _Float16* __restrict__ a, float* __restrict__ Sp, float* __restrict__ meanp)
{
  __shared__ float as8[8][132];
  const int bk = blockIdx.x;
  const size_t m0 = (size_t)bk * 256;
  const int tid = threadIdx.x;
  const int ti = tid >> 4, tj = tid & 15;

  float acc[8][8];
  #pragma unroll
  for (int ii = 0; ii < 8; ++ii)
    #pragma unroll
    for (int jj = 0; jj < 8; ++jj) acc[ii][jj] = 0.f;
  float csum = 0.f;

  for (int bt = 0; bt < 32; ++bt) {
    {
      int rr = tid >> 5, c4 = tid & 31;
      half4 hv = *(const half4*)(a + (m0 + bt * 8 + rr) * 128 + c4 * 4);
      #pragma unroll
      for (int u = 0; u < 4; ++u) as8[rr][c4 * 4 + u] = (float)hv[u];
    }
    __syncthreads();
    #pragma unroll
    for (int rr = 0; rr < 8; ++rr) {
      const float4* pi = (const float4*)(&as8[rr][ti * 8]);
      const float4* pj = (const float4*)(&as8[rr][tj * 8]);
      float4 i0 = pi[0], i1 = pi[1], j0v = pj[0], j1v = pj[1];
      float ai[8] = {i0.x, i0.y, i0.z, i0.w, i1.x, i1.y, i1.z, i1.w};
      float aj[8] = {j0v.x, j0v.y, j0v.z, j0v.w, j1v.x, j1v.y, j1v.z, j1v.w};
      #pragma unroll
      for (int ii = 0; ii < 8; ++ii)
        #pragma unroll
        for (int jj = 0; jj < 8; ++jj)
          acc[ii][jj] = fmaf(ai[ii], aj[jj], acc[ii][jj]);
    }
    if (tid < 128) {
      #pragma unroll
      for (int rr = 0; rr < 8; ++rr) csum += as8[rr][tid];
    }
    __syncthreads();
  }

  float* dstS = Sp + (size_t)bk * 16384;
  #pragma unroll
  for (int ii = 0; ii < 8; ++ii) {
    *(float4*)(dstS + (ti * 8 + ii) * 128 + tj * 8)     = make_float4(acc[ii][0], acc[ii][1], acc[ii][2], acc[ii][3]);
    *(float4*)(dstS + (ti * 8 + ii) * 128 + tj * 8 + 4) = make_float4(acc[ii][4], acc[ii][5], acc[ii][6], acc[ii][7]);
  }
  if (tid < 128) meanp[bk * 128 + tid] = csum;
}

__global__ __launch_bounds__(256) void reduce_kernel(
    const float* __restrict__ Sp, const float* __restrict__ meanp,
    float* __restrict__ S, float* __restrict__ mean)
{
  const int e = blockIdx.x * 256 + threadIdx.x;
  float s = 0.f;
  for (int bk = 0; bk < 512; ++bk) s += Sp[(size_t)bk * 16384 + e];
  S[e] = s;
  if (blockIdx.x == 0 && threadIdx.x < 128) {
    float ms = 0.f;
    for (int bk = 0; bk < 512; ++bk) ms += meanp[bk * 128 + threadIdx.x];
    mean[threadIdx.x] = ms * (1.f / (float)(B_ * N_));
  }
}

__global__ __launch_bounds__(256) void fold_kernel(
    const float* __restrict__ S, const float* __restrict__ mean,
    const float* __restrict__ ow, const float* __restrict__ ob,
    const float* __restrict__ gamma, const float* __restrict__ beta,
    float* __restrict__ w2, float* __restrict__ b2)
{
  __shared__ float scl[128];
  const int o = threadIdx.x >> 1, half = threadIdx.x & 1;
  const float* wo = ow + o * 128;
  float quad = 0.f, dm = 0.f;
  for (int i = half * 64; i < half * 64 + 64; ++i) {
    float wi = wo[i];
    float t = 0.f;
    for (int jj = 0; jj < 128; ++jj) t = fmaf(S[i * 128 + jj], wo[jj], t);
    quad = fmaf(wi, t, quad);
    dm   = fmaf(wi, mean[i], dm);
  }
  quad += __shfl_xor(quad, 1);
  dm   += __shfl_xor(dm, 1);
  if (half == 0) {
    float var = quad * (1.f / (float)(B_ * N_)) - dm * dm;
    var = fmaxf(var, 0.f);
    float sc = gamma[o] * rsqrtf(var + EPS_);
    scl[o] = sc;
    b2[o] = beta[o] - sc * dm;
  }
  __syncthreads();
  for (int e = (int)threadIdx.x; e < 16384; e += 256)
    w2[e] = scl[e >> 7] * ow[e];
}

// Final 1x1 conv with folded BN (f16 input), writes (B,D,N) f32.
__global__ __launch_bounds__(256, 2) void out_kernel(
    const _Float16* __restrict__ a, const float* __restrict__ w2,
    const float* __restrict__ b2, float* __restrict__ out)
{
  __shared__ float at[128][132];
  const int b  = blockIdx.y;
  const int n0 = blockIdx.x * 128;
  const int tid = threadIdx.x;
  {
    int row = tid >> 1, hf = tid & 1;
    const _Float16* src = a + ((size_t)b * N_ + n0 + row) * 128 + hf * 64;
    #pragma unroll
    for (int qq = 0; qq < 8; ++qq) {
      half8 v = *(const half8*)(src + qq * 8);
      #pragma unroll
      for (int u = 0; u < 8; ++u) at[hf * 64 + qq * 8 + u][row] = (float)v[u];
    }
  }
  __syncthreads();

  const int co = tid >> 4, po = tid & 15;
  float acc[8][8];
  #pragma unroll
  for (int cc = 0; cc < 8; ++cc) {
    float bv = b2[co * 8 + cc];
    #pragma unroll
    for (int pp = 0; pp < 8; ++pp) acc[cc][pp] = bv;
  }
  for (int i = 0; i < 128; ++i) {
    const float4* xr = (const float4*)(&at[i][po * 8]);
    float4 x0 = xr[0], x1 = xr[1];
    float xv[8] = {x0.x, x0.y, x0.z, x0.w, x1.x, x1.y, x1.z, x1.w};
    #pragma unroll
    for (int cc = 0; cc < 8; ++cc) {
      float wv = w2[(co * 8 + cc) * 128 + i];
      #pragma unroll
      for (int pp = 0; pp < 8; ++pp) acc[cc][pp] = fmaf(wv, xv[pp], acc[cc][pp]);
    }
  }
  #pragma unroll
  for (int cc = 0; cc < 8; ++cc) {
    int o = co * 8 + cc;
    float* dst = out + ((size_t)b * 128 + o) * N_ + n0 + po * 8;
    *(float4*)(dst)     = make_float4(acc[cc][0], acc[cc][1], acc[cc][2], acc[cc][3]);
    *(float4*)(dst + 4) = make_float4(acc[cc][4], acc[cc][5], acc[cc][6], acc[cc][7]);
  }
}

// ---------------------------------------------------------------------------
extern "C" void kernel_launch(void* const* d_in, const int* in_sizes, int n_in,
                              void* d_out, int out_size, void* d_ws, size_t ws_size,
                              hipStream_t stream)
{
  const float* x     = (const float*)d_in[0];
  const float* qw    = (const float*)d_in[1];
  const float* qb    = (const float*)d_in[2];
  const float* kw    = (const float*)d_in[3];
  const float* kb    = (const float*)d_in[4];
  const float* vw    = (const float*)d_in[5];
  const float* vb    = (const float*)d_in[6];
  const float* ow    = (const float*)d_in[7];
  const float* ob    = (const float*)d_in[8];
  const float* gamma = (const float*)d_in[9];
  const float* beta  = (const float*)d_in[10];
  float* out = (float*)d_out;
  float* ws  = (float*)d_ws;

  _Float16* q    = (_Float16*)(ws + OFF_QA);
  _Float16* k    = (_Float16*)(ws + OFF_K);
  _Float16* vT   = (_Float16*)(ws + OFF_VT);
  float* rope2   = ws + OFF_ROPE;
  _Float16* WB   = (_Float16*)(ws + OFF_WB);
  float* invf    = ws + OFF_INVF;
  float* Sp      = ws + OFF_SP;
  float* meanp   = ws + OFF_MEANP;
  float* mean    = ws + OFF_MEAN;
  float* S       = ws + OFF_S;
  float* w2      = ws + OFF_W2;
  float* b2      = ws + OFF_B2;

  invf_kernel<<<1, 64, 0, stream>>>(invf);
  rope2_kernel<<<(N_ * 64) / 256, 256, 0, stream>>>(invf, rope2);
  prepack_kernel<<<dim3(128, 5, 3), 128, 0, stream>>>(qw, kw, vw, WB);

  conv_kernel<<<dim3(N_ / 128, B_), 256, 0, stream>>>(x, WB, qb, kb, vb, q, k, vT);

  attn_kernel<<<dim3(N_ / 128, B_), 512, 0, stream>>>(q, k, vT, rope2, q /* aout aliases q */);

  stats_kernel<<<512, 256, 0, stream>>>(q, Sp, meanp);
  reduce_kernel<<<64, 256, 0, stream>>>(Sp, meanp, S, mean);
  fold_kernel<<<1, 256, 0, stream>>>(S, mean, ow, ob, gamma, beta, w2, b2);

  out_kernel<<<dim3(N_ / 128, B_), 256, 0, stream>>>(q, w2, b2, out);
}

// Round 6
// 422.241 us; speedup vs baseline: 5.0425x; 1.8276x over previous
//
#include <hip/hip_runtime.h>
#include <math.h>

#define B_   16
#define D_   128
#define N_   8192
#define EPS_ 1e-5f
#define SCALE_ 0.08838834764831845f   // 128^-0.5
#define NEG_ -3.4028235e38f

typedef _Float16 half8 __attribute__((ext_vector_type(8)));
typedef float f32x16 __attribute__((ext_vector_type(16)));
#define MFMA32(a,b,c) __builtin_amdgcn_mfma_f32_32x32x16_f16(a,b,c,0,0,0)

// Workspace layout (float offsets). High-water ~156 MB.
#define OFF_QA    0UL          // q (B,N,D) f16; aliased as attention output a
#define OFF_K     8388608UL    // k (B,N,D) f16 (pre-rotary)
#define OFF_VT    16777216UL   // v transposed (B,D,N) f16
#define OFF_AT    25165824UL   // a transposed (B,D,N) f16
#define OFF_ROPE  33554432UL   // N x 64 pairs (cos,sin) f32
#define OFF_WB    34603008UL   // prepacked conv weights f16 [c][t][o][i]
#define OFF_INVF  34725888UL   // 64 f32
#define OFF_W2H   34725952UL   // 128x128 f16 folded 1x1 weights
#define OFF_B2    34734144UL   // 128 f32
#define OFF_MEANP 34734272UL   // 256 x 128 partial colsums
#define OFF_SP    34767040UL   // 256 x 16384 partial S
#define OFF_MEAN  38961344UL   // 128
#define OFF_S     38961472UL   // 16384

// XOR-swizzled LDS index (stride 128 halfs, 16-byte blocks XOR'd by row&7)
__device__ __forceinline__ int swz(int row, int col) {
  return row * 128 + ((((col >> 3) ^ (row & 7))) << 3) + (col & 7);
}

// ---------------------------------------------------------------------------
__global__ __launch_bounds__(64) void invf_kernel(float* __restrict__ invf) {
  int j = threadIdx.x;
  invf[j] = (float)pow(10000.0, -(double)j / 64.0);
}

__global__ __launch_bounds__(256) void rope2_kernel(const float* __restrict__ invf,
                                                    float* __restrict__ rope2) {
  int idx = blockIdx.x * 256 + threadIdx.x;   // n*64 + j
  int n = idx >> 6, j = idx & 63;
  float ph = (float)n * invf[j];              // fp32 like jax
  rope2[(size_t)n * 128 + 2 * j]     = cosf(ph);
  rope2[(size_t)n * 128 + 2 * j + 1] = sinf(ph);
}

__global__ __launch_bounds__(128) void prepack_kernel(
    const float* __restrict__ qw, const float* __restrict__ kw,
    const float* __restrict__ vw, _Float16* __restrict__ WB) {
  int o = blockIdx.x, t = blockIdx.y, c = blockIdx.z, i = threadIdx.x;
  const float* w = (c == 0) ? qw : (c == 1) ? kw : vw;
  float v = w[(o * 128 + i) * 5 + t] * (c == 0 ? SCALE_ : 1.f);
  WB[(((size_t)(c * 5 + t) * 128 + o) * 128) + i] = (_Float16)v;
}

// ---------------------------------------------------------------------------
// Fused q/k/v causal conv as 5 shifted K=128 f16 GEMMs (32x32x16 MFMA).
// ---------------------------------------------------------------------------
__global__ __launch_bounds__(256, 2) void conv_kernel(
    const float* __restrict__ x, const _Float16* __restrict__ WB,
    const float* __restrict__ qb, const float* __restrict__ kb_,
    const float* __restrict__ vb,
    _Float16* __restrict__ qo, _Float16* __restrict__ ko,
    _Float16* __restrict__ vT)
{
  __shared__ _Float16 xs[132 * 128];   // [pos padded j][chan] swizzled
  __shared__ _Float16 wb[128 * 128];   // [o][i] swizzled
  const int b = blockIdx.y, n0 = blockIdx.x * 128;
  const int tid = threadIdx.x;
  const int lane = tid & 63, wq = tid >> 6;
  const int l31 = lane & 31, h = lane >> 5;

  { // stage x tile: transpose + f16 + swizzle
    int i = tid >> 1, g = tid & 1;
    const float* xrow = x + ((size_t)b * 128 + i) * (size_t)N_;
    int j0 = g * 66;
    for (int m = 0; m < 66; ++m) {
      int j = j0 + m, n = n0 - 4 + j;
      float v = (n >= 0) ? xrow[n] : 0.f;
      xs[swz(j, i)] = (_Float16)v;
    }
  }

  for (int c = 0; c < 3; ++c) {
    f32x16 acc[4];
    #pragma unroll
    for (int nt = 0; nt < 4; ++nt)
      #pragma unroll
      for (int u = 0; u < 16; ++u) acc[nt][u] = 0.f;

    for (int t = 0; t < 5; ++t) {
      __syncthreads();
      { // stage weights for (c,t): 32 KB
        const _Float16* src = WB + ((size_t)(c * 5 + t) << 14);
        #pragma unroll
        for (int m = 0; m < 8; ++m) {
          int idx = m * 256 + tid;
          int o = idx >> 4, ip = idx & 15;
          half8 v = *(const half8*)(src + o * 128 + ip * 8);
          *(half8*)(wb + o * 128 + ((ip ^ (o & 7)) << 3)) = v;
        }
      }
      __syncthreads();
      const int arow = wq * 32 + l31 + t;
      const int r7a = arow & 7;
      #pragma unroll
      for (int kb2 = 0; kb2 < 8; ++kb2) {
        half8 av = *(const half8*)(xs + arow * 128 + ((((kb2 * 2 + h) ^ r7a)) << 3));
        #pragma unroll
        for (int nt = 0; nt < 4; ++nt) {
          int o = nt * 32 + l31;
          half8 bv = *(const half8*)(wb + o * 128 + ((((kb2 * 2 + h) ^ (o & 7))) << 3));
          acc[nt] = MFMA32(av, bv, acc[nt]);
        }
      }
    }

    if (c < 2) {
      const float* bias = (c == 0) ? qb : kb_;
      float bsc = (c == 0) ? SCALE_ : 1.f;
      _Float16* outp = (c == 0) ? qo : ko;
      #pragma unroll
      for (int nt = 0; nt < 4; ++nt) {
        int o = nt * 32 + l31;
        float bv = bias[o] * bsc;
        #pragma unroll
        for (int reg = 0; reg < 16; ++reg) {
          int pos = wq * 32 + (reg & 3) + 8 * (reg >> 2) + 4 * h;
          outp[((size_t)b * N_ + n0 + pos) * 128 + o] = (_Float16)(acc[nt][reg] + bv);
        }
      }
    } else {
      // v: transpose via xs reuse -> (B,D,N)
      __syncthreads();
      #pragma unroll
      for (int nt = 0; nt < 4; ++nt) {
        int o = nt * 32 + l31;
        float bv = vb[o];
        #pragma unroll
        for (int reg = 0; reg < 16; ++reg) {
          int pos = wq * 32 + (reg & 3) + 8 * (reg >> 2) + 4 * h;
          xs[swz(o, pos)] = (_Float16)(acc[nt][reg] + bv);
        }
      }
      __syncthreads();
      int o2 = tid >> 1, g2 = tid & 1;
      _Float16* dst = vT + ((size_t)b * 128 + o2) * (size_t)N_ + n0 + g2 * 64;
      #pragma unroll
      for (int m = 0; m < 8; ++m) {
        int pos = g2 * 64 + m * 8;
        half8 v = *(const half8*)(xs + o2 * 128 + ((((pos >> 3) ^ (o2 & 7))) << 3));
        *(half8*)(dst + m * 8) = v;
      }
    }
  }
}

// ---------------------------------------------------------------------------
// Local causal attention, f16 MFMA, flash-style over 2 key chunks.
// Writes a (B,N,D) [aliases q] AND aT (B,D,N) via q_s LDS bounce.
// ---------------------------------------------------------------------------
__device__ __forceinline__ void stage_rot(const _Float16* __restrict__ src_base,
                                          _Float16* __restrict__ dst,
                                          const float* __restrict__ rope2,
                                          int nbase, int tid)
{
  int row = tid >> 2, p = tid & 3;
  const _Float16* src = src_base + (size_t)row * 128;
  const float* rp = rope2 + ((size_t)(nbase + row)) * 128 + p * 32;
  half8 lo0 = *(const half8*)(src + p * 16);
  half8 lo1 = *(const half8*)(src + p * 16 + 8);
  half8 hi0 = *(const half8*)(src + 64 + p * 16);
  half8 hi1 = *(const half8*)(src + 64 + p * 16 + 8);
  half8 olo0, olo1, ohi0, ohi1;
  #pragma unroll
  for (int u = 0; u < 8; ++u) {
    float c0 = rp[2 * u], s0 = rp[2 * u + 1];
    float c1 = rp[16 + 2 * u], s1 = rp[16 + 2 * u + 1];
    float xl0 = (float)lo0[u], xh0 = (float)hi0[u];
    float xl1 = (float)lo1[u], xh1 = (float)hi1[u];
    olo0[u] = (_Float16)(xl0 * c0 - xh0 * s0);
    ohi0[u] = (_Float16)(xh0 * c0 + xl0 * s0);
    olo1[u] = (_Float16)(xl1 * c1 - xh1 * s1);
    ohi1[u] = (_Float16)(xh1 * c1 + xl1 * s1);
  }
  int r7 = row & 7;
  *(half8*)(dst + row * 128 + (((p * 2)     ^ r7) << 3)) = olo0;
  *(half8*)(dst + row * 128 + (((p * 2 + 1) ^ r7) << 3)) = olo1;
  *(half8*)(dst + row * 128 + (((8 + p * 2) ^ r7) << 3)) = ohi0;
  *(half8*)(dst + row * 128 + (((9 + p * 2) ^ r7) << 3)) = ohi1;
}

__device__ __forceinline__ void stage_vT(const _Float16* __restrict__ vsrc,
                                         _Float16* __restrict__ dst, int tid)
{
  int d = tid >> 2, p = tid & 3;
  const _Float16* src = vsrc + (size_t)d * (size_t)N_;
  int r7 = d & 7;
  #pragma unroll
  for (int m = 0; m < 4; ++m) {
    int kp = m * 32 + p * 8;
    half8 v = *(const half8*)(src + kp);
    *(half8*)(dst + d * 128 + ((((kp >> 3) ^ r7)) << 3)) = v;
  }
}

__global__ __launch_bounds__(512, 2) void attn_kernel(
    const _Float16* __restrict__ q, const _Float16* __restrict__ k,
    const _Float16* __restrict__ vT, const float* __restrict__ rope2,
    _Float16* __restrict__ aout, _Float16* __restrict__ aTout)
{
  __shared__ _Float16 q_s[128 * 128];
  __shared__ _Float16 k_s[128 * 128];
  __shared__ _Float16 vT_s[128 * 128];
  __shared__ _Float16 P_s[128 * 128];
  __shared__ float red_m[2][128];
  __shared__ float red_s[2][128];

  const int b = blockIdx.y, w = blockIdx.x;
  const int tid = threadIdx.x, lane = tid & 63, wid = tid >> 6;
  const int wr = wid >> 1, wc = wid & 1;
  const int l31 = lane & 31, h = lane >> 5;

  stage_rot(q + ((size_t)b * N_ + w * 128) * 128, q_s, rope2, w * 128, tid);

  float mrun[16], lrun[16];
  f32x16 O[2];
  #pragma unroll
  for (int r = 0; r < 16; ++r) { mrun[r] = NEG_; lrun[r] = 0.f; O[0][r] = 0.f; O[1][r] = 0.f; }

  const int qrow = wr * 32 + l31;
  const int r7q = qrow & 7;
  int rowof[16];
  #pragma unroll
  for (int r = 0; r < 16; ++r) rowof[r] = wr * 32 + (r & 3) + 8 * (r >> 2) + 4 * h;

  for (int ch = (w == 0 ? 1 : 0); ch < 2; ++ch) {
    int kv0 = w * 128 - 128 + ch * 128;
    __syncthreads();   // protect k_s/vT_s vs prev PV; covers q_s staging on 1st iter
    stage_rot(k + ((size_t)b * N_ + kv0) * 128, k_s, rope2, kv0, tid);
    stage_vT(vT + (size_t)b * 128 * (size_t)N_ + kv0, vT_s, tid);
    __syncthreads();

    // QK^T
    f32x16 sim[2];
    #pragma unroll
    for (int r = 0; r < 16; ++r) { sim[0][r] = 0.f; sim[1][r] = 0.f; }
    #pragma unroll
    for (int kb2 = 0; kb2 < 8; ++kb2) {
      half8 av = *(const half8*)(q_s + qrow * 128 + ((((kb2 * 2 + h) ^ r7q)) << 3));
      #pragma unroll
      for (int nt = 0; nt < 2; ++nt) {
        int krow = wc * 64 + nt * 32 + l31;
        half8 bv = *(const half8*)(k_s + krow * 128 + ((((kb2 * 2 + h) ^ (krow & 7))) << 3));
        sim[nt] = MFMA32(av, bv, sim[nt]);
      }
    }
    if (ch == 1) {  // causal mask within current window
      #pragma unroll
      for (int nt = 0; nt < 2; ++nt) {
        int col = wc * 64 + nt * 32 + l31;
        #pragma unroll
        for (int r = 0; r < 16; ++r)
          if (col > rowof[r]) sim[nt][r] = NEG_;
      }
    }

    // row max (this wave's 64 cols)
    float pm[16];
    #pragma unroll
    for (int r = 0; r < 16; ++r) pm[r] = fmaxf(sim[0][r], sim[1][r]);
    #pragma unroll
    for (int m = 1; m <= 16; m <<= 1)
      #pragma unroll
      for (int r = 0; r < 16; ++r) pm[r] = fmaxf(pm[r], __shfl_xor(pm[r], m));
    if (l31 == 0) {
      #pragma unroll
      for (int r = 0; r < 16; ++r) red_m[wc][rowof[r]] = pm[r];
    }
    __syncthreads();

    float scale[16], ps[16];
    #pragma unroll
    for (int r = 0; r < 16; ++r) {
      float mc = fmaxf(red_m[0][rowof[r]], red_m[1][rowof[r]]);
      float mn = fmaxf(mrun[r], mc);
      scale[r] = __expf(mrun[r] - mn);
      mrun[r] = mn;
      ps[r] = 0.f;
    }
    #pragma unroll
    for (int nt = 0; nt < 2; ++nt) {
      int col = wc * 64 + nt * 32 + l31;
      #pragma unroll
      for (int r = 0; r < 16; ++r) {
        float p = __expf(sim[nt][r] - mrun[r]);
        ps[r] += p;
        P_s[swz(rowof[r], col)] = (_Float16)p;
      }
    }
    #pragma unroll
    for (int m = 1; m <= 16; m <<= 1)
      #pragma unroll
      for (int r = 0; r < 16; ++r) ps[r] += __shfl_xor(ps[r], m);
    if (l31 == 0) {
      #pragma unroll
      for (int r = 0; r < 16; ++r) red_s[wc][rowof[r]] = ps[r];
    }
    __syncthreads();

    #pragma unroll
    for (int r = 0; r < 16; ++r) {
      float ss = red_s[0][rowof[r]] + red_s[1][rowof[r]];
      lrun[r] = lrun[r] * scale[r] + ss;
      O[0][r] *= scale[r];
      O[1][r] *= scale[r];
    }

    // PV
    #pragma unroll
    for (int kb2 = 0; kb2 < 8; ++kb2) {
      half8 pa = *(const half8*)(P_s + qrow * 128 + ((((kb2 * 2 + h) ^ r7q)) << 3));
      #pragma unroll
      for (int nt = 0; nt < 2; ++nt) {
        int drow = wc * 64 + nt * 32 + l31;
        half8 bv = *(const half8*)(vT_s + drow * 128 + ((((kb2 * 2 + h) ^ (drow & 7))) << 3));
        O[nt] = MFMA32(pa, bv, O[nt]);
      }
    }
  }

  // epilogue: normalize, store a (B,N,D) f16 and stage transposed tile in q_s
  // (q_s is dead: last read was final QK^T, behind the red_m barrier)
  #pragma unroll
  for (int nt = 0; nt < 2; ++nt) {
    int col = wc * 64 + nt * 32 + l31;
    #pragma unroll
    for (int r = 0; r < 16; ++r) {
      float inv = 1.f / lrun[r];
      _Float16 val = (_Float16)(O[nt][r] * inv);
      aout[((size_t)b * N_ + w * 128 + rowof[r]) * 128 + col] = val;
      q_s[swz(col, rowof[r])] = val;
    }
  }
  __syncthreads();
  { // coalesced copy q_s -> aT (B,D,N)
    int d = tid >> 2, part = tid & 3;
    _Float16* dst = aTout + ((size_t)b * 128 + d) * (size_t)N_ + w * 128 + part * 32;
    #pragma unroll
    for (int mm = 0; mm < 4; ++mm) {
      int mb = part * 4 + mm;
      *(half8*)(dst + mm * 8) = *(const half8*)(q_s + d * 128 + ((mb ^ (d & 7)) << 3));
    }
  }
}

// ---------------------------------------------------------------------------
// BN stats via MFMA: partial S = a^T a and colsum from aT (B,D,N).
// 256 blocks x 512 positions; 8 sub-chunks of 64 positions in LDS.
// ---------------------------------------------------------------------------
__global__ __launch_bounds__(256, 2) void stats_kernel(
    const _Float16* __restrict__ aT, float* __restrict__ Sp, float* __restrict__ meanp)
{
  __shared__ _Float16 ts[128 * 64];   // [chan][pos] swizzled, 16 KB
  const int bk = blockIdx.x;
  const int b = bk >> 4;
  const int nbase = (bk & 15) * 512;
  const int tid = threadIdx.x, lane = tid & 63, wv = tid >> 6;
  const int l31 = lane & 31, h = lane >> 5;

  f32x16 acc[4];
  #pragma unroll
  for (int jt = 0; jt < 4; ++jt)
    #pragma unroll
    for (int u = 0; u < 16; ++u) acc[jt][u] = 0.f;
  float csum = 0.f;

  const int i2 = tid >> 1, part = tid & 1;
  const int ia = wv * 32 + l31;
  for (int sc = 0; sc < 8; ++sc) {
    __syncthreads();
    {
      const _Float16* src = aT + ((size_t)b * 128 + i2) * (size_t)N_ + nbase + sc * 64 + part * 32;
      #pragma unroll
      for (int mm = 0; mm < 4; ++mm) {
        half8 v = *(const half8*)(src + mm * 8);
        int mb = part * 4 + mm;
        *(half8*)(ts + i2 * 64 + (((mb ^ (i2 & 7))) << 3)) = v;
      }
    }
    __syncthreads();
    if (tid < 128) {  // per-channel sum (order-independent)
      #pragma unroll
      for (int mb = 0; mb < 8; ++mb) {
        half8 v = *(const half8*)(ts + tid * 64 + (((mb ^ (tid & 7))) << 3));
        #pragma unroll
        for (int u = 0; u < 8; ++u) csum += (float)v[u];
      }
    }
    #pragma unroll
    for (int kk = 0; kk < 4; ++kk) {
      int mb = kk * 2 + h;
      half8 av = *(const half8*)(ts + ia * 64 + (((mb ^ (ia & 7))) << 3));
      #pragma unroll
      for (int jt = 0; jt < 4; ++jt) {
        int jb = jt * 32 + l31;
        half8 bvv = *(const half8*)(ts + jb * 64 + (((mb ^ (jb & 7))) << 3));
        acc[jt] = MFMA32(av, bvv, acc[jt]);
      }
    }
  }
  float* dst = Sp + (size_t)bk * 16384;
  #pragma unroll
  for (int jt = 0; jt < 4; ++jt)
    #pragma unroll
    for (int r = 0; r < 16; ++r) {
      int i = wv * 32 + (r & 3) + 8 * (r >> 2) + 4 * h;
      dst[i * 128 + jt * 32 + l31] = acc[jt][r];   // S symmetric: i/j swap safe
    }
  if (tid < 128) meanp[bk * 128 + tid] = csum;
}

__global__ __launch_bounds__(256) void reduce_kernel(
    const float* __restrict__ Sp, const float* __restrict__ meanp,
    float* __restrict__ S, float* __restrict__ mean)
{
  const int e = blockIdx.x * 256 + threadIdx.x;
  float s = 0.f;
  for (int bk = 0; bk < 256; ++bk) s += Sp[(size_t)bk * 16384 + e];
  S[e] = s;
  if (blockIdx.x == 0 && threadIdx.x < 128) {
    float ms = 0.f;
    for (int bk = 0; bk < 256; ++bk) ms += meanp[bk * 128 + threadIdx.x];
    mean[threadIdx.x] = ms * (1.f / (float)(B_ * N_));
  }
}

// ---------------------------------------------------------------------------
// BN fold, parallel: 128 blocks (one per output channel) x 128 threads.
// var_y[o] = w_o^T S w_o / (BN) - (w_o . mean)^2; fold into f16 weights.
// ---------------------------------------------------------------------------
__global__ __launch_bounds__(128) void fold_kernel(
    const float* __restrict__ S, const float* __restrict__ mean,
    const float* __restrict__ ow, const float* __restrict__ gamma,
    const float* __restrict__ beta,
    _Float16* __restrict__ w2h, float* __restrict__ b2)
{
  __shared__ float wo_s[128];
  __shared__ float qred[2], dred[2];
  const int o = blockIdx.x, i = threadIdx.x;
  const int lane = i & 63, wv = i >> 6;
  float wi = ow[o * 128 + i];
  wo_s[i] = wi;
  __syncthreads();
  const float* Srow = S + i * 128;
  float t = 0.f;
  #pragma unroll 8
  for (int j = 0; j < 128; ++j) t = fmaf(Srow[j], wo_s[j], t);
  float quad = wi * t;
  float dm = wi * mean[i];
  #pragma unroll
  for (int m = 1; m <= 32; m <<= 1) {
    quad += __shfl_xor(quad, m);
    dm   += __shfl_xor(dm, m);
  }
  if (lane == 0) { qred[wv] = quad; dred[wv] = dm; }
  __syncthreads();
  float quadT = qred[0] + qred[1];
  float dmT   = dred[0] + dred[1];
  float var = quadT * (1.f / (float)(B_ * N_)) - dmT * dmT;
  var = fmaxf(var, 0.f);
  float sc = gamma[o] * rsqrtf(var + EPS_);
  if (i == 0) b2[o] = beta[o] - sc * dmT;   // o_b cancels against mean_y
  w2h[o * 128 + i] = (_Float16)(sc * wi);
}

// ---------------------------------------------------------------------------
// Final 1x1 conv via MFMA: A=w2h (o rows), B=a (pos rows) -> D col=pos
// for coalesced (B,D,N) f32 stores.
// ---------------------------------------------------------------------------
__global__ __launch_bounds__(256, 2) void out_kernel(
    const _Float16* __restrict__ a, const _Float16* __restrict__ w2h,
    const float* __restrict__ b2, float* __restrict__ out)
{
  __shared__ _Float16 a_s[128 * 128];
  __shared__ _Float16 w_s[128 * 128];
  const int b = blockIdx.y, n0 = blockIdx.x * 128;
  const int tid = threadIdx.x, lane = tid & 63, wv = tid >> 6;
  const int l31 = lane & 31, h = lane >> 5;
  {
    int row = tid >> 1, part = tid & 1;
    const _Float16* asrc = a + ((size_t)b * N_ + n0 + row) * 128 + part * 64;
    const _Float16* wsrc = w2h + row * 128 + part * 64;
    #pragma unroll
    for (int mm = 0; mm < 8; ++mm) {
      int mb = part * 8 + mm;
      int off = row * 128 + ((mb ^ (row & 7)) << 3);
      *(half8*)(a_s + off) = *(const half8*)(asrc + mm * 8);
      *(half8*)(w_s + off) = *(const half8*)(wsrc + mm * 8);
    }
  }
  __syncthreads();
  f32x16 acc[4];
  #pragma unroll
  for (int pt = 0; pt < 4; ++pt)
    #pragma unroll
    for (int u = 0; u < 16; ++u) acc[pt][u] = 0.f;
  const int orow = wv * 32 + l31;
  #pragma unroll
  for (int kk = 0; kk < 8; ++kk) {
    int mb = kk * 2 + h;
    half8 av = *(const half8*)(w_s + orow * 128 + ((mb ^ (orow & 7)) << 3));
    #pragma unroll
    for (int pt = 0; pt < 4; ++pt) {
      int prow = pt * 32 + l31;
      half8 bvv = *(const half8*)(a_s + prow * 128 + ((mb ^ (prow & 7)) << 3));
      acc[pt] = MFMA32(av, bvv, acc[pt]);
    }
  }
  float bias[16];
  int orows[16];
  #pragma unroll
  for (int r = 0; r < 16; ++r) {
    orows[r] = wv * 32 + (r & 3) + 8 * (r >> 2) + 4 * h;
    bias[r] = b2[orows[r]];
  }
  #pragma unroll
  for (int pt = 0; pt < 4; ++pt)
    #pragma unroll
    for (int r = 0; r < 16; ++r)
      out[((size_t)b * 128 + orows[r]) * N_ + n0 + pt * 32 + l31] = acc[pt][r] + bias[r];
}

// ---------------------------------------------------------------------------
extern "C" void kernel_launch(void* const* d_in, const int* in_sizes, int n_in,
                              void* d_out, int out_size, void* d_ws, size_t ws_size,
                              hipStream_t stream)
{
  const float* x     = (const float*)d_in[0];
  const float* qw    = (const float*)d_in[1];
  const float* qb    = (const float*)d_in[2];
  const float* kw    = (const float*)d_in[3];
  const float* kb    = (const float*)d_in[4];
  const float* vw    = (const float*)d_in[5];
  const float* vb    = (const float*)d_in[6];
  const float* ow    = (const float*)d_in[7];
  const float* ob    = (const float*)d_in[8];  (void)ob;
  const float* gamma = (const float*)d_in[9];
  const float* beta  = (const float*)d_in[10];
  float* out = (float*)d_out;
  float* ws  = (float*)d_ws;

  _Float16* q    = (_Float16*)(ws + OFF_QA);
  _Float16* k    = (_Float16*)(ws + OFF_K);
  _Float16* vT   = (_Float16*)(ws + OFF_VT);
  _Float16* aT   = (_Float16*)(ws + OFF_AT);
  float* rope2   = ws + OFF_ROPE;
  _Float16* WB   = (_Float16*)(ws + OFF_WB);
  float* invf    = ws + OFF_INVF;
  _Float16* w2h  = (_Float16*)(ws + OFF_W2H);
  float* b2      = ws + OFF_B2;
  float* meanp   = ws + OFF_MEANP;
  float* Sp      = ws + OFF_SP;
  float* mean    = ws + OFF_MEAN;
  float* S       = ws + OFF_S;

  invf_kernel<<<1, 64, 0, stream>>>(invf);
  rope2_kernel<<<(N_ * 64) / 256, 256, 0, stream>>>(invf, rope2);
  prepack_kernel<<<dim3(128, 5, 3), 128, 0, stream>>>(qw, kw, vw, WB);

  conv_kernel<<<dim3(N_ / 128, B_), 256, 0, stream>>>(x, WB, qb, kb, vb, q, k, vT);

  attn_kernel<<<dim3(N_ / 128, B_), 512, 0, stream>>>(q, k, vT, rope2,
                                                      q /* a aliases q */, aT);

  stats_kernel<<<256, 256, 0, stream>>>(aT, Sp, meanp);
  reduce_kernel<<<64, 256, 0, stream>>>(Sp, meanp, S, mean);
  fold_kernel<<<128, 128, 0, stream>>>(S, mean, ow, gamma, beta, w2h, b2);

  out_kernel<<<dim3(N_ / 128, B_), 256, 0, stream>>>(q, w2h, b2, out);
}